// Round 2
// baseline (402.803 us; speedup 1.0000x reference)
//
#include <hip/hip_runtime.h>

typedef unsigned int u32;

#define CG  16
#define HWN 4096

__device__ __forceinline__ float sigm(float x) { return 1.0f / (1.0f + __expf(-x)); }

union SharedU {
  struct { float row[16][64]; float col[16][64]; float cpart[16][8][64]; } p0;   // 40960 B
  struct { float row[16][64]; float col[16][64]; float RS[16][25]; float part2[16][16]; float part3[16][16]; } p1;
  float band[8][20][72];                                                          // 46080 B
};

__global__ __launch_bounds__(256, 2) void ema_kernel(
    const float* __restrict__ x,
    const float* __restrict__ w1, const float* __restrict__ b1,
    const float* __restrict__ w3, const float* __restrict__ b3,
    const float* __restrict__ w5, const float* __restrict__ b5,
    const float* __restrict__ gnw, const float* __restrict__ gnb,
    const float* __restrict__ ew, const float* __restrict__ eb,
    float* __restrict__ out)
{
  __shared__ SharedU U;
  __shared__ float s_sh[16][64];   // sigmoid(x_h2); later scaled to A1[c]*sh
  __shared__ float s_sw[16][64];   // sigmoid(x_w2)
  __shared__ float s_W5[16][28];   // effective 5x5 kernel (3x3 folded into inner taps)
  __shared__ float s_ca[16], s_A1[16], s_Cc[16];
  __shared__ float s_w1[256], s_b1[16], s_gnw[16], s_gnb[16], s_b3[16], s_b5[16], s_ecaw[3], s_ecab[1];
  __shared__ float s_m2[16], s_m3[16], s_sm1[16], s_sm2[16], s_sm3[16];
  __shared__ float s_a1[16], s_a2[16], s_a3[16], s_total[16];
  __shared__ float s_red[16][4][2];
  __shared__ float s_scal[2];      // [0]=total constant, [1]=bias_eff

  const int g = blockIdx.x;
  const int t = threadIdx.x;
  const float* px   = x   + (size_t)g * CG * HWN;
  float*       pout = out + (size_t)g * CG * HWN;

  // ---------------- Phase 0: per-channel row sums / col partial sums ----------------
  {
    const int j = t & 31, half = t >> 5;
    for (int c = 0; c < CG; ++c) {
      float ca0 = 0.f, ca1 = 0.f;
      for (int k = 0; k < 8; ++k) {
        const int y = half * 8 + k;
        float2 v = *(const float2*)(px + c * HWN + y * 64 + 2 * j);
        ca0 += v.x; ca1 += v.y;
        float rp = v.x + v.y;
        rp += __shfl_xor(rp, 1);  rp += __shfl_xor(rp, 2);
        rp += __shfl_xor(rp, 4);  rp += __shfl_xor(rp, 8);
        rp += __shfl_xor(rp, 16);
        if (j == 0) U.p0.row[c][y] = rp;
      }
      U.p0.cpart[c][half][2*j]   = ca0;
      U.p0.cpart[c][half][2*j+1] = ca1;
    }
  }
  // small weight vectors -> LDS
  s_w1[t] = w1[t];
  if (t < 16) {
    s_b1[t]  = b1[t];  s_gnw[t] = gnw[t]; s_gnb[t] = gnb[t];
    s_b3[t]  = b3[t];  s_b5[t]  = b5[t];
  }
  if (t < 3)  s_ecaw[t] = ew[t];
  if (t == 0) s_ecab[0] = eb[0];
  __syncthreads();

  // finalize col sums
  for (int m = 0; m < 4; ++m) {
    int o = t + 256*m; int c = o >> 6, xx = o & 63;
    float s = 0.f;
    #pragma unroll
    for (int h = 0; h < 8; ++h) s += U.p0.cpart[c][h][xx];
    U.p0.col[c][xx] = s;
  }
  __syncthreads();
  if (t < 16) { float s = 0.f; for (int y = 0; y < 64; ++y) s += U.p1.row[t][y]; s_total[t] = s; }
  __syncthreads();

  // ---------------- conv1x1 (+sigmoid) over [x_h ; x_w], and 5x5 region sums ----------------
  for (int m = 0; m < 8; ++m) {
    int idx = t + 256*m; int o = idx >> 7, pos = idx & 127;
    float acc = s_b1[o];
    const float inv64 = 1.0f/64.0f;
    #pragma unroll
    for (int i = 0; i < 16; ++i) {
      float v = (pos < 64 ? U.p1.row[i][pos] : U.p1.col[i][pos-64]) * inv64;
      acc += s_w1[o*16+i] * v;
    }
    float sg = sigm(acc);
    if (pos < 64) s_sh[o][pos] = sg; else s_sw[o][pos-64] = sg;
  }
  for (int m = 0; m < 2; ++m) {
    int task = t + 256*m;
    if (task < 400) {
      int i = task / 25, kk = task % 25;
      int dy = kk/5 - 2, dx = kk%5 - 2;
      int a  = dy > 0 ? dy : 0,   b  = 64 + (dy < 0 ? dy : 0);
      int cl = dx > 0 ? dx : 0,   d  = 64 + (dx < 0 ? dx : 0);
      float S = s_total[i];
      if (a > 0)  S -= U.p1.row[i][0];
      if (a > 1)  S -= U.p1.row[i][1];
      if (b < 64) S -= U.p1.row[i][63];
      if (b < 63) S -= U.p1.row[i][62];
      // subtract out-of-window full columns (restricted to rows [a,b))
      for (int x0 = 0; x0 < cl; ++x0) {
        float cv = U.p1.col[i][x0];
        if (a > 0)  cv -= px[i*HWN + 0*64  + x0];
        if (a > 1)  cv -= px[i*HWN + 1*64  + x0];
        if (b < 64) cv -= px[i*HWN + 63*64 + x0];
        if (b < 63) cv -= px[i*HWN + 62*64 + x0];
        S -= cv;
      }
      for (int x0 = d; x0 < 64; ++x0) {
        float cv = U.p1.col[i][x0];
        if (a > 0)  cv -= px[i*HWN + 0*64  + x0];
        if (a > 1)  cv -= px[i*HWN + 1*64  + x0];
        if (b < 64) cv -= px[i*HWN + 63*64 + x0];
        if (b < 63) cv -= px[i*HWN + 62*64 + x0];
        S -= cv;
      }
      U.p1.RS[i][kk] = S;
    }
  }
  __syncthreads();

  // ---------------- mean(x2), mean(x3) via region sums ----------------
  {
    int o = t >> 4, i = t & 15;
    float p2 = 0.f, p3 = 0.f;
    const float* w3b = w3 + (o*16+i)*9;
    const float* w5b = w5 + (o*16+i)*25;
    #pragma unroll
    for (int ky = 0; ky < 3; ++ky)
      #pragma unroll
      for (int kx = 0; kx < 3; ++kx)
        p2 += w3b[ky*3+kx] * U.p1.RS[i][(ky+1)*5 + (kx+1)];
    #pragma unroll
    for (int kk = 0; kk < 25; ++kk) p3 += w5b[kk] * U.p1.RS[i][kk];
    U.p1.part2[o][i] = p2; U.p1.part3[o][i] = p3;
  }
  __syncthreads();
  if (t < 16)      { float s=0.f; for (int i=0;i<16;++i) s += U.p1.part2[t][i];    s_m2[t] = s_b3[t] + s*(1.0f/4096.0f); }
  else if (t < 32) { int o=t-16; float s=0.f; for (int i=0;i<16;++i) s += U.p1.part3[o][i]; s_m3[o] = s_b5[o] + s*(1.0f/4096.0f); }
  __syncthreads();

  // ---------------- softmaxes over channel means (mean(x1) == gn_b exactly) ----------------
  if (t < 3) {
    const float* m = (t==0) ? s_gnb : (t==1) ? s_m2 : s_m3;
    float* dst     = (t==0) ? s_sm1 : (t==1) ? s_sm2 : s_sm3;
    float mx = m[0];
    for (int c = 1; c < 16; ++c) mx = fmaxf(mx, m[c]);
    float e[16], ssum = 0.f;
    for (int c = 0; c < 16; ++c) { e[c] = __expf(m[c]-mx); ssum += e[c]; }
    float r = 1.0f/ssum;
    for (int c = 0; c < 16; ++c) dst[c] = e[c]*r;
  }
  __syncthreads();

  // ---------------- ECA (-> ca) and mixing coefficients ----------------
  if (t < 16) {
    int c = t;
    float casum = 0.f;
    #pragma unroll
    for (int v = 0; v < 3; ++v) {
      const float* m = (v==0) ? s_gnb : (v==1) ? s_m2 : s_m3;
      float acc = s_ecab[0] + s_ecaw[1]*m[c];
      if (c > 0)  acc += s_ecaw[0]*m[c-1];
      if (c < 15) acc += s_ecaw[2]*m[c+1];
      casum += sigm(acc);
    }
    s_ca[c] = casum;
    s_a1[c] = s_sm2[c] + s_sm3[c];
    s_a2[c] = s_sm1[c] + s_sm3[c];
    s_a3[c] = s_sm1[c] + s_sm2[c];
  }
  __syncthreads();

  // ---------------- effective 5x5 kernel (3x3 folded) + bias ----------------
  if (t == 0) {
    float s = 0.f;
    for (int o = 0; o < 16; ++o) s += s_a2[o]*s_b3[o] + s_a3[o]*s_b5[o];
    s_scal[1] = s;
  }
  for (int m = 0; m < 2; ++m) {
    int task = t + 256*m;
    if (task < 400) {
      int i = task/25, kk = task%25, ky = kk/5, kx = kk%5;
      float acc = 0.f;
      #pragma unroll
      for (int o = 0; o < 16; ++o) acc += s_a3[o]*w5[((o*16+i)*5+ky)*5+kx];
      if (ky >= 1 && ky <= 3 && kx >= 1 && kx <= 3) {
        #pragma unroll
        for (int o = 0; o < 16; ++o) acc += s_a2[o]*w3[((o*16+i)*3+(ky-1))*3+(kx-1)];
      }
      s_W5[i][kk] = acc;
    }
  }
  __syncthreads();

  // ---------------- Phase A: GroupNorm stats of gated = X*sh(y)*sw(x) ----------------
  {
    const int x0 = (t & 7) * 8;
    const int yA = t >> 3, yB = yA + 32;
    const int wv4 = t >> 6;
    #pragma unroll 1
    for (int c = 0; c < 16; ++c) {
      float sw8[8];
      #pragma unroll
      for (int i = 0; i < 8; ++i) sw8[i] = s_sw[c][x0+i];
      float shA = s_sh[c][yA], shB = s_sh[c][yB];
      float4 a0 = *(const float4*)(px + c*HWN + yA*64 + x0);
      float4 a1 = *(const float4*)(px + c*HWN + yA*64 + x0 + 4);
      float4 b0 = *(const float4*)(px + c*HWN + yB*64 + x0);
      float4 b1 = *(const float4*)(px + c*HWN + yB*64 + x0 + 4);
      float va[8] = {a0.x,a0.y,a0.z,a0.w,a1.x,a1.y,a1.z,a1.w};
      float vb[8] = {b0.x,b0.y,b0.z,b0.w,b1.x,b1.y,b1.z,b1.w};
      float gsl = 0.f, gql = 0.f;
      #pragma unroll
      for (int i = 0; i < 8; ++i) {
        float ga = va[i] * shA * sw8[i];
        float gb = vb[i] * shB * sw8[i];
        gsl += ga + gb; gql += ga*ga + gb*gb;
      }
      float a = gsl, b2 = gql;
      a += __shfl_xor(a, 1);  b2 += __shfl_xor(b2, 1);
      a += __shfl_xor(a, 2);  b2 += __shfl_xor(b2, 2);
      a += __shfl_xor(a, 4);  b2 += __shfl_xor(b2, 4);
      a += __shfl_xor(a, 8);  b2 += __shfl_xor(b2, 8);
      a += __shfl_xor(a, 16); b2 += __shfl_xor(b2, 16);
      a += __shfl_xor(a, 32); b2 += __shfl_xor(b2, 32);
      if ((t & 63) == 0) { s_red[c][wv4][0] = a; s_red[c][wv4][1] = b2; }
    }
  }
  __syncthreads();
  if (t < 16) {
    int c = t;
    float S = 0.f, Q = 0.f;
    #pragma unroll
    for (int w = 0; w < 4; ++w) { S += s_red[c][w][0]; Q += s_red[c][w][1]; }
    float mu  = S * (1.0f/4096.0f);
    float var = Q * (1.0f/4096.0f) - mu*mu;
    float inv = rsqrtf(var + 1e-5f);
    s_A1[c] = s_a1[c] * s_gnw[c] * inv;
    s_Cc[c] = s_a1[c] * (s_gnb[c] - mu * s_gnw[c] * inv);
  }
  __syncthreads();
  if (t == 0) { float s = s_scal[1]; for (int c = 0; c < 16; ++c) s += s_Cc[c]; s_scal[0] = s; }
  for (int m = 0; m < 4; ++m) { int idx = t + 256*m; int c = idx >> 6, y = idx & 63; s_sh[c][y] *= s_A1[c]; }
  __syncthreads();

  // ---------------- Phase B: banded fused 5x5 conv + gated term + epilogue ----------------
  // one-time zero of entire band buffer (establishes col pads 0..3, 68..71 = 0)
  for (int m = 0; m < 12; ++m) { int idx = t + 256*m; if (idx < 2880) ((float4*)U.band)[idx] = make_float4(0.f,0.f,0.f,0.f); }
  __syncthreads();

  const int lane = t & 63, wv = t >> 6;
  const float Cc = s_scal[0];
  for (int band = 0; band < 4; ++band) {
    const int yb = band * 16;
    float ws[4] = {Cc, Cc, Cc, Cc};
    for (int half = 0; half < 2; ++half) {
      __syncthreads();   // previous compute (or zeroing) done before restage
      // stage rows yb-2 .. yb+17 for 8 channels; OOB rows stored as zero
      for (int k = 0; k < 10; ++k) {
        int q = t + 256*k;               // 2560 float4 tasks, exact
        int rr = q >> 4, xc = (q & 15) * 4;
        int c = rr / 20, yy = rr % 20;
        int y = yb + yy - 2;
        float4 v = make_float4(0.f,0.f,0.f,0.f);
        if ((unsigned)y < 64u) v = *(const float4*)(px + (half*8+c)*HWN + y*64 + xc);
        *(float4*)&U.band[c][yy][4 + xc] = v;
      }
      __syncthreads();

      #pragma unroll 1
      for (int c = 0; c < 8; ++c) {
        const int ch = half*8 + c;
        float Wk[25];
        #pragma unroll
        for (int kk = 0; kk < 25; ++kk) Wk[kk] = s_W5[ch][kk];
        float swv = s_sw[ch][lane];
        float ash[4];
        #pragma unroll
        for (int r = 0; r < 4; ++r) ash[r] = s_sh[ch][yb + 4*wv + r];
        const float* bp = &U.band[c][4*wv][lane + 2];
        #pragma unroll
        for (int q = 0; q < 8; ++q) {
          const float* rowp = bp + q*72;
          float v0 = rowp[0];
          float v1 = rowp[1];
          float v2 = rowp[2];
          float v3 = rowp[3];
          float v4 = rowp[4];
          #pragma unroll
          for (int r = 0; r < 4; ++r) {
            const int kr = q - r;
            if (kr >= 0 && kr <= 4) {
              ws[r] += Wk[kr*5+0]*v0 + Wk[kr*5+1]*v1 + Wk[kr*5+2]*v2 + Wk[kr*5+3]*v3 + Wk[kr*5+4]*v4;
              if (kr == 2) ws[r] += ash[r] * (v2 * swv);   // gated x1 term (center tap)
            }
          }
        }
      }
    }
    // epilogue: out = X * ca[c] * sigmoid(ws); X re-read from global (L2-hot)
    #pragma unroll
    for (int r = 0; r < 4; ++r) {
      float sg = sigm(ws[r]);
      int y = yb + 4*wv + r;
      const float* xp = px   + y*64 + lane;
      float*       op = pout + y*64 + lane;
      #pragma unroll
      for (int c = 0; c < 16; ++c) {
        op[c*HWN] = xp[c*HWN] * s_ca[c] * sg;
      }
    }
  }
}

extern "C" void kernel_launch(void* const* d_in, const int* in_sizes, int n_in,
                              void* d_out, int out_size, void* d_ws, size_t ws_size,
                              hipStream_t stream) {
  const float* X  = (const float*)d_in[0];
  const float* W1 = (const float*)d_in[1];
  const float* B1 = (const float*)d_in[2];
  const float* W3 = (const float*)d_in[3];
  const float* B3 = (const float*)d_in[4];
  const float* W5 = (const float*)d_in[5];
  const float* B5 = (const float*)d_in[6];
  const float* GW = (const float*)d_in[7];
  const float* GB = (const float*)d_in[8];
  const float* EW = (const float*)d_in[9];
  const float* EB = (const float*)d_in[10];
  float* O = (float*)d_out;
  ema_kernel<<<dim3(512), dim3(256), 0, stream>>>(X, W1, B1, W3, B3, W5, B5, GW, GB, EW, EB, O);
}

// Round 3
// 345.495 us; speedup vs baseline: 1.1659x; 1.1659x over previous
//
#include <hip/hip_runtime.h>

typedef unsigned int u32;

#define CG   16
#define HWN  4096
#define LSTR 72

__device__ __forceinline__ float sigm(float x) { return 1.0f / (1.0f + __expf(-x)); }

union SharedU {
  struct {
    float row[16][64];
    float col[16][64];
    union {
      float cwave[16][4][64];
      struct { float RS[16][25]; float part2[16][16]; float part3[16][16]; } r;
    } u;
  } p;                              // 24576 B
  float cb[2][68][LSTR];            // 39168 B (double-buffered channel tile, pad 2 all around)
};

__global__ __launch_bounds__(256, 2) void ema_kernel(
    const float* __restrict__ x,
    const float* __restrict__ w1, const float* __restrict__ b1,
    const float* __restrict__ w3, const float* __restrict__ b3,
    const float* __restrict__ w5, const float* __restrict__ b5,
    const float* __restrict__ gnw, const float* __restrict__ gnb,
    const float* __restrict__ ew, const float* __restrict__ eb,
    float* __restrict__ out)
{
  __shared__ SharedU U;
  __shared__ float s_sh[16][64];   // sigmoid(x_h2); later scaled to A1[c]*sh
  __shared__ float s_sw[16][64];   // sigmoid(x_w2)
  __shared__ float s_W5[16][28];   // effective 5x5 kernel (3x3 folded), padded to 28
  __shared__ float s_ca[16], s_A1[16], s_Cc[16];
  __shared__ float s_w1[256], s_b1[16], s_gnw[16], s_gnb[16], s_b3[16], s_b5[16], s_ecaw[3], s_ecab[1];
  __shared__ float s_m2[16], s_m3[16], s_sm1[16], s_sm2[16], s_sm3[16];
  __shared__ float s_a1[16], s_a2[16], s_a3[16], s_total[16];
  __shared__ float s_red[16][4][2];
  __shared__ float s_scal[2];      // [0]=total constant, [1]=bias_eff

  const int g = blockIdx.x;
  const int t = threadIdx.x;
  const float* px   = x   + (size_t)g * CG * HWN;
  float*       pout = out + (size_t)g * CG * HWN;

  // ---------------- Phase 1: per-channel row sums / col sums (float4, in-wave reduce) ----------------
  {
    const int j4 = t & 15, hh = t >> 4, wv4 = t >> 6;
    for (int c = 0; c < CG; ++c) {
      float cp0 = 0.f, cp1 = 0.f, cp2 = 0.f, cp3 = 0.f;
      #pragma unroll
      for (int k = 0; k < 4; ++k) {
        int y = 4 * hh + k;
        float4 v = *(const float4*)(px + c * HWN + y * 64 + 4 * j4);
        float rs = v.x + v.y + v.z + v.w;
        rs += __shfl_xor(rs, 1); rs += __shfl_xor(rs, 2);
        rs += __shfl_xor(rs, 4); rs += __shfl_xor(rs, 8);
        if (j4 == 0) U.p.row[c][y] = rs;
        cp0 += v.x; cp1 += v.y; cp2 += v.z; cp3 += v.w;
      }
      cp0 += __shfl_xor(cp0, 16); cp0 += __shfl_xor(cp0, 32);
      cp1 += __shfl_xor(cp1, 16); cp1 += __shfl_xor(cp1, 32);
      cp2 += __shfl_xor(cp2, 16); cp2 += __shfl_xor(cp2, 32);
      cp3 += __shfl_xor(cp3, 16); cp3 += __shfl_xor(cp3, 32);
      if ((t & 48) == 0) *(float4*)&U.p.u.cwave[c][wv4][4 * j4] = make_float4(cp0, cp1, cp2, cp3);
    }
  }
  // small weight vectors -> LDS
  s_w1[t] = w1[t];
  if (t < 16) {
    s_b1[t]  = b1[t];  s_gnw[t] = gnw[t]; s_gnb[t] = gnb[t];
    s_b3[t]  = b3[t];  s_b5[t]  = b5[t];
  }
  if (t < 3)  s_ecaw[t] = ew[t];
  if (t == 0) s_ecab[0] = eb[0];
  __syncthreads();

  // finalize col sums (sum the 4 per-wave partials)
  {
    int c = t >> 4, q = t & 15;
    float4 s = make_float4(0.f, 0.f, 0.f, 0.f);
    #pragma unroll
    for (int w = 0; w < 4; ++w) {
      float4 v = *(float4*)&U.p.u.cwave[c][w][4 * q];
      s.x += v.x; s.y += v.y; s.z += v.z; s.w += v.w;
    }
    *(float4*)&U.p.col[c][4 * q] = s;
  }
  __syncthreads();
  if (t < 16) { float s = 0.f; for (int y = 0; y < 64; ++y) s += U.p.row[t][y]; s_total[t] = s; }
  __syncthreads();

  // ---------------- conv1x1 (+sigmoid) over [x_h ; x_w], and 5x5 region sums ----------------
  for (int m = 0; m < 8; ++m) {
    int idx = t + 256 * m; int o = idx >> 7, pos = idx & 127;
    float acc = s_b1[o];
    const float inv64 = 1.0f / 64.0f;
    #pragma unroll
    for (int i = 0; i < 16; ++i) {
      float v = (pos < 64 ? U.p.row[i][pos] : U.p.col[i][pos - 64]) * inv64;
      acc += s_w1[o * 16 + i] * v;
    }
    float sg = sigm(acc);
    if (pos < 64) s_sh[o][pos] = sg; else s_sw[o][pos - 64] = sg;
  }
  for (int m = 0; m < 2; ++m) {
    int task = t + 256 * m;
    if (task < 400) {
      int i = task / 25, kk = task % 25;
      int dy = kk / 5 - 2, dx = kk % 5 - 2;
      int a  = dy > 0 ? dy : 0,   b  = 64 + (dy < 0 ? dy : 0);
      int cl = dx > 0 ? dx : 0,   d  = 64 + (dx < 0 ? dx : 0);
      float S = s_total[i];
      if (a > 0)  S -= U.p.row[i][0];
      if (a > 1)  S -= U.p.row[i][1];
      if (b < 64) S -= U.p.row[i][63];
      if (b < 63) S -= U.p.row[i][62];
      for (int x0 = 0; x0 < cl; ++x0) {
        float cv = U.p.col[i][x0];
        if (a > 0)  cv -= px[i * HWN + 0 * 64  + x0];
        if (a > 1)  cv -= px[i * HWN + 1 * 64  + x0];
        if (b < 64) cv -= px[i * HWN + 63 * 64 + x0];
        if (b < 63) cv -= px[i * HWN + 62 * 64 + x0];
        S -= cv;
      }
      for (int x0 = d; x0 < 64; ++x0) {
        float cv = U.p.col[i][x0];
        if (a > 0)  cv -= px[i * HWN + 0 * 64  + x0];
        if (a > 1)  cv -= px[i * HWN + 1 * 64  + x0];
        if (b < 64) cv -= px[i * HWN + 63 * 64 + x0];
        if (b < 63) cv -= px[i * HWN + 62 * 64 + x0];
        S -= cv;
      }
      U.p.u.r.RS[i][kk] = S;
    }
  }
  __syncthreads();

  // ---------------- mean(x2), mean(x3) via region sums ----------------
  {
    int o = t >> 4, i = t & 15;
    float p2 = 0.f, p3 = 0.f;
    const float* w3b = w3 + (o * 16 + i) * 9;
    const float* w5b = w5 + (o * 16 + i) * 25;
    #pragma unroll
    for (int ky = 0; ky < 3; ++ky)
      #pragma unroll
      for (int kx = 0; kx < 3; ++kx)
        p2 += w3b[ky * 3 + kx] * U.p.u.r.RS[i][(ky + 1) * 5 + (kx + 1)];
    #pragma unroll
    for (int kk = 0; kk < 25; ++kk) p3 += w5b[kk] * U.p.u.r.RS[i][kk];
    U.p.u.r.part2[o][i] = p2; U.p.u.r.part3[o][i] = p3;
  }
  __syncthreads();
  if (t < 16)      { float s = 0.f; for (int i = 0; i < 16; ++i) s += U.p.u.r.part2[t][i];    s_m2[t] = s_b3[t] + s * (1.0f/4096.0f); }
  else if (t < 32) { int o = t - 16; float s = 0.f; for (int i = 0; i < 16; ++i) s += U.p.u.r.part3[o][i]; s_m3[o] = s_b5[o] + s * (1.0f/4096.0f); }
  __syncthreads();

  // ---------------- softmaxes over channel means (mean(x1) == gn_b exactly) ----------------
  if (t < 3) {
    const float* m = (t == 0) ? s_gnb : (t == 1) ? s_m2 : s_m3;
    float* dst     = (t == 0) ? s_sm1 : (t == 1) ? s_sm2 : s_sm3;
    float mx = m[0];
    for (int c = 1; c < 16; ++c) mx = fmaxf(mx, m[c]);
    float e[16], ssum = 0.f;
    for (int c = 0; c < 16; ++c) { e[c] = __expf(m[c] - mx); ssum += e[c]; }
    float r = 1.0f / ssum;
    for (int c = 0; c < 16; ++c) dst[c] = e[c] * r;
  }
  __syncthreads();

  // ---------------- ECA (-> ca) and mixing coefficients ----------------
  if (t < 16) {
    int c = t;
    float casum = 0.f;
    #pragma unroll
    for (int v = 0; v < 3; ++v) {
      const float* m = (v == 0) ? s_gnb : (v == 1) ? s_m2 : s_m3;
      float acc = s_ecab[0] + s_ecaw[1] * m[c];
      if (c > 0)  acc += s_ecaw[0] * m[c - 1];
      if (c < 15) acc += s_ecaw[2] * m[c + 1];
      casum += sigm(acc);
    }
    s_ca[c] = casum;
    s_a1[c] = s_sm2[c] + s_sm3[c];
    s_a2[c] = s_sm1[c] + s_sm3[c];
    s_a3[c] = s_sm1[c] + s_sm2[c];
  }
  __syncthreads();

  // ---------------- effective 5x5 kernel (3x3 folded) + bias ----------------
  if (t == 0) {
    float s = 0.f;
    for (int o = 0; o < 16; ++o) s += s_a2[o] * s_b3[o] + s_a3[o] * s_b5[o];
    s_scal[1] = s;
  }
  for (int m = 0; m < 2; ++m) {
    int task = t + 256 * m;
    if (task < 400) {
      int i = task / 25, kk = task % 25, ky = kk / 5, kx = kk % 5;
      float acc = 0.f;
      #pragma unroll
      for (int o = 0; o < 16; ++o) acc += s_a3[o] * w5[((o * 16 + i) * 5 + ky) * 5 + kx];
      if (ky >= 1 && ky <= 3 && kx >= 1 && kx <= 3) {
        #pragma unroll
        for (int o = 0; o < 16; ++o) acc += s_a2[o] * w3[((o * 16 + i) * 3 + (ky - 1)) * 3 + (kx - 1)];
      }
      s_W5[i][kk] = acc;
    }
    else if (task < 448) { int i = (task - 400) / 3; s_W5[i][25 + (task - 400) % 3] = 0.f; }
  }
  __syncthreads();

  // ---------------- Phase 3: zero padded tiles once, then fused conv + GN stats sweep ----------------
  for (int m = 0; m < 10; ++m) { int idx = t + 256 * m; if (idx < 2448) ((float4*)U.cb)[idx] = make_float4(0.f, 0.f, 0.f, 0.f); }
  __syncthreads();

  const int x0 = 4 * (t & 15), y0 = 4 * (t >> 4), wv4 = t >> 6;

  // stage channel c into buffer buf (float2 writes keep 8B alignment at col offset 2)
  #define STAGE(buf, c) {                                              \
    _Pragma("unroll")                                                  \
    for (int k = 0; k < 4; ++k) {                                      \
      int q = t + 256 * k;                                             \
      int rr = q >> 4, xc = (q & 15) * 4;                              \
      float4 v = *(const float4*)(px + (c) * HWN + rr * 64 + xc);      \
      float* d = &U.cb[buf][2 + rr][2 + xc];                           \
      *(float2*)d       = make_float2(v.x, v.y);                       \
      *(float2*)(d + 2) = make_float2(v.z, v.w);                       \
    }                                                                  \
  }

  float ws[16];
  #pragma unroll
  for (int i = 0; i < 16; ++i) ws[i] = 0.f;

  STAGE(0, 0);
  __syncthreads();
  #pragma unroll 1
  for (int c = 0; c < 16; ++c) {
    if (c < 15) STAGE((c + 1) & 1, c + 1);
    float Wk[28];
    #pragma unroll
    for (int i = 0; i < 7; ++i) *(float4*)&Wk[4 * i] = *(float4*)&s_W5[c][4 * i];
    float shv[4], swv[4];
    #pragma unroll
    for (int r = 0; r < 4; ++r) { shv[r] = s_sh[c][y0 + r]; swv[r] = s_sw[c][x0 + r]; }
    const float* base = &U.cb[c & 1][0][0];
    float gsl = 0.f, gql = 0.f;
    #pragma unroll
    for (int q = 0; q < 8; ++q) {
      const float* rp = base + (y0 + q) * LSTR + x0;
      float4 A = *(const float4*)rp, B = *(const float4*)(rp + 4);
      float v[8] = {A.x, A.y, A.z, A.w, B.x, B.y, B.z, B.w};
      if (q >= 2 && q <= 5) {               // GN stats of gated = X*sh(y)*sw(x) (center values)
        const int ry = q - 2;
        #pragma unroll
        for (int m = 0; m < 4; ++m) { float gg = v[m + 2] * shv[ry] * swv[m]; gsl += gg; gql += gg * gg; }
      }
      #pragma unroll
      for (int r = 0; r < 4; ++r) {
        if (q - r >= 0 && q - r <= 4) {
          const int kr = q - r;
          #pragma unroll
          for (int m = 0; m < 4; ++m) {
            float a = ws[4 * r + m];
            a += Wk[kr * 5 + 0] * v[m + 0];
            a += Wk[kr * 5 + 1] * v[m + 1];
            a += Wk[kr * 5 + 2] * v[m + 2];
            a += Wk[kr * 5 + 3] * v[m + 3];
            a += Wk[kr * 5 + 4] * v[m + 4];
            ws[4 * r + m] = a;
          }
        }
      }
    }
    gsl += __shfl_xor(gsl, 1);  gql += __shfl_xor(gql, 1);
    gsl += __shfl_xor(gsl, 2);  gql += __shfl_xor(gql, 2);
    gsl += __shfl_xor(gsl, 4);  gql += __shfl_xor(gql, 4);
    gsl += __shfl_xor(gsl, 8);  gql += __shfl_xor(gql, 8);
    gsl += __shfl_xor(gsl, 16); gql += __shfl_xor(gql, 16);
    gsl += __shfl_xor(gsl, 32); gql += __shfl_xor(gql, 32);
    if ((t & 63) == 0) { s_red[c][wv4][0] = gsl; s_red[c][wv4][1] = gql; }
    __syncthreads();
  }

  // ---------------- GN finalize ----------------
  if (t < 16) {
    int c = t;
    float S = 0.f, Q = 0.f;
    #pragma unroll
    for (int w = 0; w < 4; ++w) { S += s_red[c][w][0]; Q += s_red[c][w][1]; }
    float mu  = S * (1.0f / 4096.0f);
    float var = Q * (1.0f / 4096.0f) - mu * mu;
    float inv = rsqrtf(var + 1e-5f);
    s_A1[c] = s_a1[c] * s_gnw[c] * inv;
    s_Cc[c] = s_a1[c] * (s_gnb[c] - mu * s_gnw[c] * inv);
  }
  __syncthreads();
  if (t == 0) { float s = s_scal[1]; for (int c = 0; c < 16; ++c) s += s_Cc[c]; s_scal[0] = s; }
  for (int m = 0; m < 4; ++m) { int idx = t + 256 * m; int c = idx >> 6, y = idx & 63; s_sh[c][y] *= s_A1[c]; }
  __syncthreads();

  // ---------------- Epilogue: gated term from re-read X, then out = X * ca * sigmoid(ws) ----------------
  float gws[16];
  #pragma unroll
  for (int i = 0; i < 16; ++i) gws[i] = 0.f;
  #pragma unroll 1
  for (int c = 0; c < 16; ++c) {
    float shv[4], swv[4];
    #pragma unroll
    for (int r = 0; r < 4; ++r) { shv[r] = s_sh[c][y0 + r]; swv[r] = s_sw[c][x0 + r]; }
    #pragma unroll
    for (int r = 0; r < 4; ++r) {
      float4 xv = *(const float4*)(px + c * HWN + (y0 + r) * 64 + x0);
      gws[4 * r + 0] += shv[r] * swv[0] * xv.x;
      gws[4 * r + 1] += shv[r] * swv[1] * xv.y;
      gws[4 * r + 2] += shv[r] * swv[2] * xv.z;
      gws[4 * r + 3] += shv[r] * swv[3] * xv.w;
    }
  }
  {
    const float Cc = s_scal[0];
    #pragma unroll
    for (int i = 0; i < 16; ++i) ws[i] = sigm(ws[i] + gws[i] + Cc);
  }
  #pragma unroll 1
  for (int c = 0; c < 16; ++c) {
    float cav = s_ca[c];
    #pragma unroll
    for (int r = 0; r < 4; ++r) {
      float4 xv = *(const float4*)(px + c * HWN + (y0 + r) * 64 + x0);
      float4 o;
      o.x = xv.x * cav * ws[4 * r + 0];
      o.y = xv.y * cav * ws[4 * r + 1];
      o.z = xv.z * cav * ws[4 * r + 2];
      o.w = xv.w * cav * ws[4 * r + 3];
      *(float4*)(pout + c * HWN + (y0 + r) * 64 + x0) = o;
    }
  }
}

extern "C" void kernel_launch(void* const* d_in, const int* in_sizes, int n_in,
                              void* d_out, int out_size, void* d_ws, size_t ws_size,
                              hipStream_t stream) {
  const float* X  = (const float*)d_in[0];
  const float* W1 = (const float*)d_in[1];
  const float* B1 = (const float*)d_in[2];
  const float* W3 = (const float*)d_in[3];
  const float* B3 = (const float*)d_in[4];
  const float* W5 = (const float*)d_in[5];
  const float* B5 = (const float*)d_in[6];
  const float* GW = (const float*)d_in[7];
  const float* GB = (const float*)d_in[8];
  const float* EW = (const float*)d_in[9];
  const float* EB = (const float*)d_in[10];
  float* O = (float*)d_out;
  ema_kernel<<<dim3(512), dim3(256), 0, stream>>>(X, W1, B1, W3, B3, W5, B5, GW, GB, EW, EB, O);
}

// Round 4
// 345.313 us; speedup vs baseline: 1.1665x; 1.0005x over previous
//
#include <hip/hip_runtime.h>

typedef unsigned int u32;

#define CG   16
#define HWN  4096
#define LSTR 68

__device__ __forceinline__ float sigm(float x) { return 1.0f / (1.0f + __expf(-x)); }

__global__ __launch_bounds__(512, 4) void ema_kernel(
    const float* __restrict__ x,
    const float* __restrict__ w1, const float* __restrict__ b1,
    const float* __restrict__ w3, const float* __restrict__ b3,
    const float* __restrict__ w5, const float* __restrict__ b5,
    const float* __restrict__ gnw, const float* __restrict__ gnb,
    const float* __restrict__ ew, const float* __restrict__ eb,
    float* __restrict__ out)
{
  __shared__ __align__(16) float s_cb[2][68][LSTR];  // 36992 B channel tile, pad 2 all around
  __shared__ __align__(16) float s_row[16][64];
  __shared__ __align__(16) float s_col[16][64];
  __shared__ __align__(16) float s_RS[16][25];
  __shared__ float s_p2[16][16], s_p3[16][16];
  __shared__ __align__(16) float s_sh[16][64];   // sigmoid(x_h2)
  __shared__ __align__(16) float s_sw[16][64];   // sigmoid(x_w2)
  __shared__ __align__(16) float s_W5[16][28];   // effective 5x5 kernel (3x3 folded), padded
  __shared__ float s_ca[16], s_A1[16], s_Cc[16];
  __shared__ float s_w1[256], s_b1[16], s_gnw[16], s_gnb[16], s_b3[16], s_b5[16], s_ecaw[3], s_ecab[1];
  __shared__ float s_m2[16], s_m3[16], s_sm1[16], s_sm2[16], s_sm3[16];
  __shared__ float s_a1[16], s_a2[16], s_a3[16], s_total[16];
  __shared__ float s_red[16][8][2];
  __shared__ float s_scal[2];      // [0]=total constant, [1]=bias_eff

  const int g = blockIdx.x;
  const int t = threadIdx.x;
  const int wv = t >> 6;           // wave 0..7
  const int ln = t & 63;
  const float* px   = x   + (size_t)g * CG * HWN;
  float*       pout = out + (size_t)g * CG * HWN;

  // ---------------- Phase 1: row/col sums; wave w owns channels 2w, 2w+1 ----------------
  {
    const int j4 = ln & 15;        // col group (4 cols)
    const int rr = ln >> 4;        // 0..3 row phase
    #pragma unroll 1
    for (int cc = 0; cc < 2; ++cc) {
      const int c = 2 * wv + cc;
      float rs[16];
      float cp0 = 0.f, cp1 = 0.f, cp2 = 0.f, cp3 = 0.f;
      #pragma unroll
      for (int j = 0; j < 16; ++j) {
        float4 v = *(const float4*)(px + c * HWN + (rr + 4 * j) * 64 + 4 * j4);
        rs[j] = v.x + v.y + v.z + v.w;
        cp0 += v.x; cp1 += v.y; cp2 += v.z; cp3 += v.w;
      }
      #pragma unroll
      for (int j = 0; j < 16; ++j) {
        float r = rs[j];
        r += __shfl_xor(r, 1); r += __shfl_xor(r, 2);
        r += __shfl_xor(r, 4); r += __shfl_xor(r, 8);
        if (j4 == 0) s_row[c][rr + 4 * j] = r;
      }
      cp0 += __shfl_xor(cp0, 16); cp0 += __shfl_xor(cp0, 32);
      cp1 += __shfl_xor(cp1, 16); cp1 += __shfl_xor(cp1, 32);
      cp2 += __shfl_xor(cp2, 16); cp2 += __shfl_xor(cp2, 32);
      cp3 += __shfl_xor(cp3, 16); cp3 += __shfl_xor(cp3, 32);
      if (rr == 0) *(float4*)&s_col[c][4 * j4] = make_float4(cp0, cp1, cp2, cp3);
    }
  }
  // small weight vectors -> LDS
  if (t < 256) s_w1[t] = w1[t];
  if (t < 16) {
    s_b1[t]  = b1[t];  s_gnw[t] = gnw[t]; s_gnb[t] = gnb[t];
    s_b3[t]  = b3[t];  s_b5[t]  = b5[t];
  }
  if (t < 3)  s_ecaw[t] = ew[t];
  if (t == 0) s_ecab[0] = eb[0];
  __syncthreads();

  if (t < 16) { float s = 0.f; for (int y = 0; y < 64; ++y) s += s_row[t][y]; s_total[t] = s; }
  __syncthreads();

  // ---------------- conv1x1 (+sigmoid), zero cb tile, 5x5 region sums ----------------
  #pragma unroll
  for (int m = 0; m < 4; ++m) {
    int idx = t + 512 * m; int o = idx >> 7, pos = idx & 127;
    float acc = s_b1[o];
    const float inv64 = 1.0f / 64.0f;
    #pragma unroll
    for (int i = 0; i < 16; ++i) {
      float v = (pos < 64 ? s_row[i][pos] : s_col[i][pos - 64]) * inv64;
      acc += s_w1[o * 16 + i] * v;
    }
    float sg = sigm(acc);
    if (pos < 64) s_sh[o][pos] = sg; else s_sw[o][pos - 64] = sg;
  }
  #pragma unroll
  for (int m = 0; m < 5; ++m) { int idx = t + 512 * m; if (idx < 2312) ((float4*)s_cb)[idx] = make_float4(0.f, 0.f, 0.f, 0.f); }
  if (t < 400) {
    int i = t / 25, kk = t % 25;
    int dy = kk / 5 - 2, dx = kk % 5 - 2;
    int a  = dy > 0 ? dy : 0,   b  = 64 + (dy < 0 ? dy : 0);
    int cl = dx > 0 ? dx : 0,   d  = 64 + (dx < 0 ? dx : 0);
    float S = s_total[i];
    if (a > 0)  S -= s_row[i][0];
    if (a > 1)  S -= s_row[i][1];
    if (b < 64) S -= s_row[i][63];
    if (b < 63) S -= s_row[i][62];
    for (int x0 = 0; x0 < cl; ++x0) {
      float cv = s_col[i][x0];
      if (a > 0)  cv -= px[i * HWN + 0 * 64  + x0];
      if (a > 1)  cv -= px[i * HWN + 1 * 64  + x0];
      if (b < 64) cv -= px[i * HWN + 63 * 64 + x0];
      if (b < 63) cv -= px[i * HWN + 62 * 64 + x0];
      S -= cv;
    }
    for (int x0 = d; x0 < 64; ++x0) {
      float cv = s_col[i][x0];
      if (a > 0)  cv -= px[i * HWN + 0 * 64  + x0];
      if (a > 1)  cv -= px[i * HWN + 1 * 64  + x0];
      if (b < 64) cv -= px[i * HWN + 63 * 64 + x0];
      if (b < 63) cv -= px[i * HWN + 62 * 64 + x0];
      S -= cv;
    }
    s_RS[i][kk] = S;
  }
  __syncthreads();

  // ---------------- mean(x2), mean(x3) via region sums ----------------
  if (t < 256) {
    int o = t >> 4, i = t & 15;
    float p2 = 0.f, p3 = 0.f;
    const float* w3b = w3 + (o * 16 + i) * 9;
    const float* w5b = w5 + (o * 16 + i) * 25;
    #pragma unroll
    for (int ky = 0; ky < 3; ++ky)
      #pragma unroll
      for (int kx = 0; kx < 3; ++kx)
        p2 += w3b[ky * 3 + kx] * s_RS[i][(ky + 1) * 5 + (kx + 1)];
    #pragma unroll
    for (int kk = 0; kk < 25; ++kk) p3 += w5b[kk] * s_RS[i][kk];
    s_p2[o][i] = p2; s_p3[o][i] = p3;
  }
  __syncthreads();
  if (t < 16)      { float s = 0.f; for (int i = 0; i < 16; ++i) s += s_p2[t][i];      s_m2[t] = s_b3[t] + s * (1.0f/4096.0f); }
  else if (t < 32) { int o = t - 16; float s = 0.f; for (int i = 0; i < 16; ++i) s += s_p3[o][i]; s_m3[o] = s_b5[o] + s * (1.0f/4096.0f); }
  __syncthreads();

  // ---------------- softmaxes over channel means (mean(x1) == gn_b exactly) ----------------
  if (t < 3) {
    const float* m = (t == 0) ? s_gnb : (t == 1) ? s_m2 : s_m3;
    float* dst     = (t == 0) ? s_sm1 : (t == 1) ? s_sm2 : s_sm3;
    float mx = m[0];
    for (int c = 1; c < 16; ++c) mx = fmaxf(mx, m[c]);
    float e[16], ssum = 0.f;
    for (int c = 0; c < 16; ++c) { e[c] = __expf(m[c] - mx); ssum += e[c]; }
    float r = 1.0f / ssum;
    for (int c = 0; c < 16; ++c) dst[c] = e[c] * r;
  }
  __syncthreads();

  // ---------------- ECA (-> ca) and mixing coefficients ----------------
  if (t < 16) {
    int c = t;
    float casum = 0.f;
    #pragma unroll
    for (int v = 0; v < 3; ++v) {
      const float* m = (v == 0) ? s_gnb : (v == 1) ? s_m2 : s_m3;
      float acc = s_ecab[0] + s_ecaw[1] * m[c];
      if (c > 0)  acc += s_ecaw[0] * m[c - 1];
      if (c < 15) acc += s_ecaw[2] * m[c + 1];
      casum += sigm(acc);
    }
    s_ca[c] = casum;
    s_a1[c] = s_sm2[c] + s_sm3[c];
    s_a2[c] = s_sm1[c] + s_sm3[c];
    s_a3[c] = s_sm1[c] + s_sm2[c];
  }
  __syncthreads();

  // ---------------- effective 5x5 kernel (3x3 folded) + bias; prefetch ch0 stage ----------------
  // stage channel (c) into buffer (buf): 1024 float4 tasks over 512 threads
  #define STAGE(buf, c) {                                                \
    _Pragma("unroll")                                                    \
    for (int k = 0; k < 2; ++k) {                                        \
      int q = t + 512 * k;                                               \
      int rr = q >> 4, xc = (q & 15) * 4;                                \
      float4 v = *(const float4*)(px + (size_t)(c) * HWN + rr * 64 + xc);\
      float* d = &s_cb[buf][2 + rr][2 + xc];                             \
      *(float2*)d       = make_float2(v.x, v.y);                         \
      *(float2*)(d + 2) = make_float2(v.z, v.w);                         \
    }                                                                    \
  }

  if (t == 0) {
    float s = 0.f;
    for (int o = 0; o < 16; ++o) s += s_a2[o] * s_b3[o] + s_a3[o] * s_b5[o];
    s_scal[1] = s;
  }
  if (t < 448) {
    if (t < 400) {
      int i = t / 25, kk = t % 25, ky = kk / 5, kx = kk % 5;
      float acc = 0.f;
      #pragma unroll
      for (int o = 0; o < 16; ++o) acc += s_a3[o] * w5[((o * 16 + i) * 5 + ky) * 5 + kx];
      if (ky >= 1 && ky <= 3 && kx >= 1 && kx <= 3) {
        #pragma unroll
        for (int o = 0; o < 16; ++o) acc += s_a2[o] * w3[((o * 16 + i) * 3 + (ky - 1)) * 3 + (kx - 1)];
      }
      s_W5[i][kk] = acc;
    } else {
      int q = t - 400; s_W5[q / 3][25 + q % 3] = 0.f;
    }
  }
  STAGE(0, 0);
  __syncthreads();

  // ---------------- Conv sweep: 2x4 tile/thread, pipelined GN->A1->gated fold ----------------
  const int x0 = 4 * (t & 15);
  const int y0 = 2 * (t >> 4);     // 0..62

  float ws[8];
  #pragma unroll
  for (int i = 0; i < 8; ++i) ws[i] = 0.f;
  float gsv[2][8];

  #pragma unroll 1
  for (int c = 0; c < 16; ++c) {
    if (c < 15) STAGE((c + 1) & 1, c + 1);
    // finalize GN stats of channel c-1 (s_red written in iter c-1, visible after barrier)
    if (c >= 1 && t == 0) {
      float S = 0.f, Q = 0.f;
      #pragma unroll
      for (int w = 0; w < 8; ++w) { S += s_red[c-1][w][0]; Q += s_red[c-1][w][1]; }
      float mu  = S * (1.0f / 4096.0f);
      float var = Q * (1.0f / 4096.0f) - mu * mu;
      float inv = rsqrtf(var + 1e-5f);
      s_A1[c-1] = s_a1[c-1] * s_gnw[c-1] * inv;
      s_Cc[c-1] = s_a1[c-1] * (s_gnb[c-1] - mu * s_gnw[c-1] * inv);
    }
    // fold gated term of channel c-2 (A1[c-2] finalized in iter c-1, barrier since)
    if (c >= 2) {
      float a1v = s_A1[c-2];
      #pragma unroll
      for (int i = 0; i < 8; ++i) ws[i] += a1v * gsv[c & 1][i];
    }
    float Wk[28];
    #pragma unroll
    for (int i = 0; i < 7; ++i) *(float4*)&Wk[4 * i] = *(float4*)&s_W5[c][4 * i];
    float shv0 = s_sh[c][y0], shv1 = s_sh[c][y0 + 1];
    float swv[4];
    #pragma unroll
    for (int r = 0; r < 4; ++r) swv[r] = s_sw[c][x0 + r];
    const float* base = &s_cb[c & 1][0][0] + y0 * LSTR + x0;
    float gsl = 0.f, gql = 0.f;
    #pragma unroll
    for (int q = 0; q < 6; ++q) {
      const float* rp = base + q * LSTR;
      float4 A = *(const float4*)rp, B = *(const float4*)(rp + 4);
      float v[8] = {A.x, A.y, A.z, A.w, B.x, B.y, B.z, B.w};
      if (q == 2 || q == 3) {          // center rows: GN stats + save gated values
        const float sh_ = (q == 2) ? shv0 : shv1;
        const int ri = q - 2;
        #pragma unroll
        for (int m = 0; m < 4; ++m) {
          float gg = v[m + 2] * sh_ * swv[m];
          gsl += gg; gql += gg * gg;
          gsv[c & 1][4 * ri + m] = gg;
        }
      }
      #pragma unroll
      for (int r = 0; r < 2; ++r) {
        const int kr = q - r;
        if (kr >= 0 && kr <= 4) {
          #pragma unroll
          for (int m = 0; m < 4; ++m) {
            float a = ws[4 * r + m];
            a += Wk[kr * 5 + 0] * v[m + 0];
            a += Wk[kr * 5 + 1] * v[m + 1];
            a += Wk[kr * 5 + 2] * v[m + 2];
            a += Wk[kr * 5 + 3] * v[m + 3];
            a += Wk[kr * 5 + 4] * v[m + 4];
            ws[4 * r + m] = a;
          }
        }
      }
    }
    gsl += __shfl_xor(gsl, 1);  gql += __shfl_xor(gql, 1);
    gsl += __shfl_xor(gsl, 2);  gql += __shfl_xor(gql, 2);
    gsl += __shfl_xor(gsl, 4);  gql += __shfl_xor(gql, 4);
    gsl += __shfl_xor(gsl, 8);  gql += __shfl_xor(gql, 8);
    gsl += __shfl_xor(gsl, 16); gql += __shfl_xor(gql, 16);
    gsl += __shfl_xor(gsl, 32); gql += __shfl_xor(gql, 32);
    if (ln == 0) { s_red[c][wv][0] = gsl; s_red[c][wv][1] = gql; }
    __syncthreads();
  }

  // ---------------- tail: finalize ch15, total constant, fold ch14/ch15 ----------------
  if (t == 0) {
    float S = 0.f, Q = 0.f;
    #pragma unroll
    for (int w = 0; w < 8; ++w) { S += s_red[15][w][0]; Q += s_red[15][w][1]; }
    float mu  = S * (1.0f / 4096.0f);
    float var = Q * (1.0f / 4096.0f) - mu * mu;
    float inv = rsqrtf(var + 1e-5f);
    s_A1[15] = s_a1[15] * s_gnw[15] * inv;
    s_Cc[15] = s_a1[15] * (s_gnb[15] - mu * s_gnw[15] * inv);
    float s = s_scal[1];
    for (int c = 0; c < 16; ++c) s += s_Cc[c];
    s_scal[0] = s;
  }
  __syncthreads();
  {
    const float a14 = s_A1[14], a15 = s_A1[15], Ct = s_scal[0];
    #pragma unroll
    for (int i = 0; i < 8; ++i)
      ws[i] = sigm(ws[i] + a14 * gsv[0][i] + a15 * gsv[1][i] + Ct);
  }

  // ---------------- Epilogue: out = X * ca[c] * sigmoid(weights) ----------------
  #pragma unroll
  for (int c = 0; c < 16; ++c) {
    const float cav = s_ca[c];
    const float* xp = px   + c * HWN + y0 * 64 + x0;
    float*       op = pout + c * HWN + y0 * 64 + x0;
    float4 xa = *(const float4*)xp;
    float4 xb = *(const float4*)(xp + 64);
    float4 oa, ob;
    oa.x = xa.x * cav * ws[0]; oa.y = xa.y * cav * ws[1];
    oa.z = xa.z * cav * ws[2]; oa.w = xa.w * cav * ws[3];
    ob.x = xb.x * cav * ws[4]; ob.y = xb.y * cav * ws[5];
    ob.z = xb.z * cav * ws[6]; ob.w = xb.w * cav * ws[7];
    *(float4*)op        = oa;
    *(float4*)(op + 64) = ob;
  }
}

extern "C" void kernel_launch(void* const* d_in, const int* in_sizes, int n_in,
                              void* d_out, int out_size, void* d_ws, size_t ws_size,
                              hipStream_t stream) {
  const float* X  = (const float*)d_in[0];
  const float* W1 = (const float*)d_in[1];
  const float* B1 = (const float*)d_in[2];
  const float* W3 = (const float*)d_in[3];
  const float* B3 = (const float*)d_in[4];
  const float* W5 = (const float*)d_in[5];
  const float* B5 = (const float*)d_in[6];
  const float* GW = (const float*)d_in[7];
  const float* GB = (const float*)d_in[8];
  const float* EW = (const float*)d_in[9];
  const float* EB = (const float*)d_in[10];
  float* O = (float*)d_out;
  ema_kernel<<<dim3(512), dim3(512), 0, stream>>>(X, W1, B1, W3, B3, W5, B5, GW, GB, EW, EB, O);
}